// Round 1
// baseline (499.938 us; speedup 1.0000x reference)
//
#include <hip/hip_runtime.h>
#include <stdint.h>

#define BB 64
#define PP 24656
#define CC 81
#define NEGPOS 3

// ws layout:
//   [0..31]    4 doubles: loss_l, loss_o, loss_c_pos, loss_c_sel
//   [64..319]  int num_pos[64]
//   [512..]    float mine[BB*PP]   (~6.31 MB)

__global__ __launch_bounds__(256) void k_main(
    const float* __restrict__ loc_data,
    const float* __restrict__ conf_data,
    const float* __restrict__ occ_data,
    const float* __restrict__ loc_t,
    const int*   __restrict__ conf_t,
    const float* __restrict__ occ_t,
    double* __restrict__ accum,   // 4 doubles
    int* __restrict__ num_pos,    // 64 ints
    float* __restrict__ mine)     // BB*PP floats
{
    const int lane = threadIdx.x & 63;
    const int wib  = threadIdx.x >> 6;
    const long wave_id = (long)blockIdx.x * (blockDim.x >> 6) + wib;
    const long n_waves = (long)gridDim.x * (blockDim.x >> 6);
    const long total = (long)BB * PP;

    double a_l = 0.0, a_o = 0.0, a_cp = 0.0;

    for (long i = wave_id; i < total; i += n_waves) {
        const float* row = conf_data + i * CC;
        float x0 = row[lane];
        float x1 = (lane < CC - 64) ? row[64 + lane] : -3.0e38f;
        float m = fmaxf(x0, x1);
        #pragma unroll
        for (int s = 1; s < 64; s <<= 1) m = fmaxf(m, __shfl_xor(m, s, 64));
        float ssum = expf(x0 - m) + ((lane < CC - 64) ? expf(x1 - m) : 0.0f);
        #pragma unroll
        for (int s = 1; s < 64; s <<= 1) ssum += __shfl_xor(ssum, s, 64);

        if (lane == 0) {
            float lse = m + logf(ssum);
            int t = conf_t[i];
            float cat = row[t];
            float diff = lse - cat;           // >= 0 always
            bool pos = t > 0;
            mine[i] = pos ? 0.0f : diff;
            if (pos) {
                atomicAdd(&num_pos[(int)(i / PP)], 1);
                a_cp += (double)diff;
                const float* ld = loc_data + i * 4;
                const float* lt = loc_t + i * 4;
                float sl = 0.0f;
                #pragma unroll
                for (int j = 0; j < 4; ++j) {
                    float d = ld[j] - lt[j];
                    float ad = fabsf(d);
                    sl += (ad < 1.0f) ? 0.5f * d * d : ad - 0.5f;
                }
                a_l += (double)sl;
                float ot = occ_t[i];
                if (ot != -1.0f) {
                    float dd = occ_data[i] - ot;
                    a_o += (double)(dd * dd);
                }
            }
        }
    }

    __shared__ double red[3][4];
    if (lane == 0) { red[0][wib] = a_l; red[1][wib] = a_o; red[2][wib] = a_cp; }
    __syncthreads();
    if (threadIdx.x == 0) {
        double t0 = 0, t1 = 0, t2 = 0;
        #pragma unroll
        for (int w = 0; w < 4; ++w) { t0 += red[0][w]; t1 += red[1][w]; t2 += red[2][w]; }
        atomicAdd(&accum[0], t0);
        atomicAdd(&accum[1], t1);
        atomicAdd(&accum[2], t2);
    }
}

// One block per batch row: radix-select k-th largest of mine[row,:], then
// loss_c_neg = sum(v > thr) + (k - count_gt) * thr   (exact under stable-sort ties)
__global__ __launch_bounds__(1024) void k_select(
    const float* __restrict__ mine,
    const int* __restrict__ num_pos,
    double* __restrict__ accum)
{
    __shared__ float vals[PP];                  // 98624 B
    __shared__ unsigned int hist16[16][256];    // 16384 B
    __shared__ unsigned int hist[256];
    __shared__ unsigned int sh_prefix, sh_mask, sh_k;
    __shared__ double dred[16];
    __shared__ unsigned int cred[16];

    const int b = blockIdx.x;
    const int tid = threadIdx.x;
    const int lane = tid & 63;
    const int w = tid >> 6;
    const float* row = mine + (long)b * PP;

    for (int i = tid; i < PP; i += 1024) vals[i] = row[i];

    int np = num_pos[b];
    int k = NEGPOS * np;
    if (k > PP - 1) k = PP - 1;
    __syncthreads();
    if (k <= 0) return;   // uniform across block

    unsigned int prefix = 0, maskhi = 0, kk = (unsigned int)k;

    for (int pass = 0; pass < 4; ++pass) {
        const int shift = 24 - 8 * pass;
        // zero sub-histograms
        for (int i = tid; i < 16 * 256; i += 1024) ((unsigned int*)hist16)[i] = 0;
        __syncthreads();
        for (int i = tid; i < PP; i += 1024) {
            unsigned int u = __float_as_uint(vals[i]);
            if ((u & maskhi) == prefix)
                atomicAdd(&hist16[w][(u >> shift) & 255], 1u);
        }
        __syncthreads();
        if (tid < 256) {
            unsigned int s = 0;
            #pragma unroll
            for (int j = 0; j < 16; ++j) s += hist16[j][tid];
            hist[tid] = s;
        }
        __syncthreads();
        if (tid == 0) {
            unsigned int cum = 0; int bsel = 0;
            for (int bb = 255; bb >= 0; --bb) {
                unsigned int c = hist[bb];
                if (cum + c >= kk) { bsel = bb; break; }
                cum += c;
            }
            sh_k = kk - cum;
            sh_prefix = prefix | ((unsigned int)bsel << shift);
            sh_mask = maskhi | (0xFFu << shift);
        }
        __syncthreads();
        prefix = sh_prefix; maskhi = sh_mask; kk = sh_k;
        __syncthreads();
    }

    const unsigned int thr_bits = prefix;
    const float thr = __uint_as_float(thr_bits);

    double ssum = 0.0;
    unsigned int cnt = 0;
    for (int i = tid; i < PP; i += 1024) {
        float v = vals[i];
        if (__float_as_uint(v) > thr_bits) { ssum += (double)v; cnt++; }
    }
    #pragma unroll
    for (int s = 1; s < 64; s <<= 1) {
        ssum += __shfl_xor(ssum, s, 64);
        cnt  += __shfl_xor(cnt, s, 64);
    }
    if (lane == 0) { dred[w] = ssum; cred[w] = cnt; }
    __syncthreads();
    if (tid == 0) {
        double S = 0; unsigned int cg = 0;
        #pragma unroll
        for (int j = 0; j < 16; ++j) { S += dred[j]; cg += cred[j]; }
        S += (double)(k - (int)cg) * (double)thr;
        atomicAdd(&accum[3], S);
    }
}

__global__ void k_final(const double* __restrict__ accum,
                        const int* __restrict__ num_pos,
                        float* __restrict__ out)
{
    if (threadIdx.x == 0 && blockIdx.x == 0) {
        int N = 0;
        for (int b = 0; b < BB; ++b) N += num_pos[b];
        double dN = (double)N;
        out[0] = (float)(accum[0] / dN);                 // loss_l / N
        out[1] = (float)((accum[2] + accum[3]) / dN);    // loss_c / N
        out[2] = (float)(accum[1] / dN);                 // loss_o / N
    }
}

extern "C" void kernel_launch(void* const* d_in, const int* in_sizes, int n_in,
                              void* d_out, int out_size, void* d_ws, size_t ws_size,
                              hipStream_t stream) {
    const float* loc_data  = (const float*)d_in[0];
    const float* conf_data = (const float*)d_in[1];
    const float* occ_data  = (const float*)d_in[2];
    const float* loc_t     = (const float*)d_in[3];
    const int*   conf_t    = (const int*)d_in[4];
    const float* occ_t     = (const float*)d_in[5];

    char* ws = (char*)d_ws;
    double* accum  = (double*)ws;          // 4 doubles
    int*    numpos = (int*)(ws + 64);      // 64 ints
    float*  mine   = (float*)(ws + 512);   // BB*PP floats

    hipMemsetAsync(ws, 0, 512, stream);

    k_main<<<2048, 256, 0, stream>>>(loc_data, conf_data, occ_data, loc_t,
                                     conf_t, occ_t, accum, numpos, mine);
    k_select<<<BB, 1024, 0, stream>>>(mine, numpos, accum);
    k_final<<<1, 64, 0, stream>>>(accum, numpos, (float*)d_out);
}

// Round 2
// 333.539 us; speedup vs baseline: 1.4989x; 1.4989x over previous
//
#include <hip/hip_runtime.h>
#include <stdint.h>

#define BB 64
#define PP 24656
#define CC 81
#define NEGPOS 3
#define TROWS 128
#define TBYTES (TROWS * CC * 4)        // 41472 = 40*1024 + 512
#define NTILES ((BB * PP) / TROWS)     // 12328 exactly
#define NSLOT 256

// ws layout:
//   [0]        double csel               (8 B)
//   [64]       int num_pos[64]           (256 B)
//   [512]      double acc[NSLOT*3]       (6144 B)  l,o,cp per slot
//   [8192]     float mine[BB*PP]         (~6.31 MB)

typedef unsigned int u32;

__device__ __forceinline__ void gload_lds16(const void* g, void* l) {
    __builtin_amdgcn_global_load_lds(
        (const __attribute__((address_space(1))) u32*)g,
        (__attribute__((address_space(3))) u32*)l, 16, 0, 0);
}
__device__ __forceinline__ void gload_lds4(const void* g, void* l) {
    __builtin_amdgcn_global_load_lds(
        (const __attribute__((address_space(1))) u32*)g,
        (__attribute__((address_space(3))) u32*)l, 4, 0, 0);
}

__global__ __launch_bounds__(256) void k_main(
    const float* __restrict__ loc_data,
    const float* __restrict__ conf_data,
    const float* __restrict__ occ_data,
    const float* __restrict__ loc_t,
    const int*   __restrict__ conf_t,
    const float* __restrict__ occ_t,
    double* __restrict__ acc,     // NSLOT*3
    int* __restrict__ num_pos,    // 64
    float* __restrict__ mine)     // BB*PP
{
    __shared__ float tile[TROWS * CC];   // 41472 B
    __shared__ double red[4][3];

    const int t = threadIdx.x;
    const int w = t >> 6;
    const int lane = t & 63;
    const int tileIdx = blockIdx.x;
    const char* gbase = (const char*)(conf_data) + (long)tileIdx * TBYTES;

    // ---- stage tile: 40 x 1024B chunks (size16) + 2 x 256B tail (size4) ----
    #pragma unroll
    for (int c = 0; c < 10; ++c) {
        const int off = ((c << 2) + w) << 10;   // (4c+w)*1024
        gload_lds16(gbase + off + (lane << 4), (char*)tile + off);
    }
    if (w == 0) {
        gload_lds4(gbase + 40960 + (lane << 2), (char*)tile + 40960);
        gload_lds4(gbase + 41216 + (lane << 2), (char*)tile + 41216);
    }
    asm volatile("s_waitcnt vmcnt(0)" ::: "memory");
    __syncthreads();

    // ---- compute: 2 threads per row ----
    const int rl = t >> 1;          // local row 0..127
    const int h  = t & 1;
    const long i = (long)tileIdx * TROWS + rl;
    const float* rp = tile + rl * CC + (h ? 41 : 0);
    const int n = h ? 40 : 41;

    float s = 0.0f;
    #pragma unroll 8
    for (int j = 0; j < n; ++j) s += __expf(rp[j]);
    s += __shfl_xor(s, 1, 64);      // merge the two halves of the row

    double a_l = 0.0, a_o = 0.0, a_cp = 0.0;
    if (h == 0) {
        const int tc = conf_t[i];
        const float cat = tile[rl * CC + tc];
        const float lse = __logf(s);
        const float diff = lse - cat;
        if (tc > 0) {
            a_cp = (double)diff;
            const float* ld = loc_data + i * 4;
            const float* lt = loc_t + i * 4;
            float sl = 0.0f;
            #pragma unroll
            for (int j = 0; j < 4; ++j) {
                float d = ld[j] - lt[j];
                float ad = fabsf(d);
                sl += (ad < 1.0f) ? 0.5f * d * d : ad - 0.5f;
            }
            a_l = (double)sl;
            const float ot = occ_t[i];
            if (ot != -1.0f) {
                float dd = occ_data[i] - ot;
                a_o = (double)(dd * dd);
            }
            atomicAdd(&num_pos[(int)(i / PP)], 1);
            mine[i] = 0.0f;
        } else {
            mine[i] = fmaxf(diff, 0.0f);   // mining value, strictly > 0 in exact math
        }
    }

    // ---- block reduction of the three partial sums ----
    #pragma unroll
    for (int sft = 1; sft < 64; sft <<= 1) {
        a_l  += __shfl_xor(a_l,  sft, 64);
        a_o  += __shfl_xor(a_o,  sft, 64);
        a_cp += __shfl_xor(a_cp, sft, 64);
    }
    if (lane == 0) { red[w][0] = a_l; red[w][1] = a_o; red[w][2] = a_cp; }
    __syncthreads();
    if (t == 0) {
        double x0 = red[0][0] + red[1][0] + red[2][0] + red[3][0];
        double x1 = red[0][1] + red[1][1] + red[2][1] + red[3][1];
        double x2 = red[0][2] + red[1][2] + red[2][2] + red[3][2];
        const int slot = tileIdx & (NSLOT - 1);
        atomicAdd(&acc[slot * 3 + 0], x0);
        atomicAdd(&acc[slot * 3 + 1], x1);
        atomicAdd(&acc[slot * 3 + 2], x2);
    }
}

// One block per batch row, values register-resident (25 per thread).
__global__ __launch_bounds__(1024) void k_select(
    const float* __restrict__ mine,
    const int* __restrict__ num_pos,
    double* __restrict__ csel)
{
    __shared__ u32 hist16[16][256];   // per-wave sub-histograms
    __shared__ u32 htot[256];
    __shared__ u32 sh_prefix, sh_kk;
    __shared__ double dred[16];
    __shared__ u32 cred[16];

    const int b = blockIdx.x;
    const int t = threadIdx.x;
    const int w = t >> 6;
    const int lane = t & 63;
    const float* row = mine + (long)b * PP;

    u32 u[25];
    #pragma unroll
    for (int r = 0; r < 25; ++r) {
        const int idx = t + (r << 10);
        u[r] = (idx < PP) ? __float_as_uint(row[idx]) : 0u;  // pad with +0.0 (sorts last)
    }

    const int np = num_pos[b];
    int k = NEGPOS * np;
    if (k > PP - 1) k = PP - 1;
    if (k <= 0) return;   // uniform across block

    u32 prefix = 0, mask = 0, kk = (u32)k;

    for (int pass = 0; pass < 4; ++pass) {
        const int shift = 24 - 8 * pass;
        for (int z = t; z < 16 * 256; z += 1024) ((u32*)hist16)[z] = 0;
        __syncthreads();
        #pragma unroll
        for (int r = 0; r < 25; ++r) {
            const u32 uu = u[r];
            if ((uu & mask) == prefix)
                atomicAdd(&hist16[w][(uu >> shift) & 255], 1u);
        }
        __syncthreads();
        if (t < 256) {
            u32 s2 = 0;
            #pragma unroll
            for (int j = 0; j < 16; ++j) s2 += hist16[j][t];
            htot[t] = s2;
        }
        __syncthreads();
        if (t < 256) {
            u32 above = 0;
            for (int bb = t + 1; bb < 256; ++bb) above += htot[bb];
            if (above < kk && above + htot[t] >= kk) {   // exactly one bin satisfies this
                sh_prefix = prefix | ((u32)t << shift);
                sh_kk = kk - above;
            }
        }
        __syncthreads();
        prefix = sh_prefix;
        kk = sh_kk;
        mask |= (0xFFu << shift);
        __syncthreads();
    }

    const u32 thr_bits = prefix;
    const float thr = __uint_as_float(thr_bits);

    double ssum = 0.0;
    u32 cnt = 0;
    #pragma unroll
    for (int r = 0; r < 25; ++r) {
        const u32 uu = u[r];
        if (uu > thr_bits) { ssum += (double)__uint_as_float(uu); cnt++; }
    }
    #pragma unroll
    for (int sft = 1; sft < 64; sft <<= 1) {
        ssum += __shfl_xor(ssum, sft, 64);
        cnt  += __shfl_xor(cnt,  sft, 64);
    }
    if (lane == 0) { dred[w] = ssum; cred[w] = cnt; }
    __syncthreads();
    if (t == 0) {
        double S = 0.0; u32 cg = 0;
        #pragma unroll
        for (int j = 0; j < 16; ++j) { S += dred[j]; cg += cred[j]; }
        S += (double)(k - (int)cg) * (double)thr;   // ties at threshold value
        atomicAdd(csel, S);
    }
}

__global__ __launch_bounds__(256) void k_final(
    const double* __restrict__ acc,
    const double* __restrict__ csel,
    const int* __restrict__ num_pos,
    float* __restrict__ out)
{
    __shared__ double red[4][4];
    const int t = threadIdx.x;
    const int w = t >> 6;
    const int lane = t & 63;

    double l = acc[t * 3 + 0];
    double o = acc[t * 3 + 1];
    double c = acc[t * 3 + 2];
    double npd = (t < BB) ? (double)num_pos[t] : 0.0;
    #pragma unroll
    for (int sft = 1; sft < 64; sft <<= 1) {
        l   += __shfl_xor(l,   sft, 64);
        o   += __shfl_xor(o,   sft, 64);
        c   += __shfl_xor(c,   sft, 64);
        npd += __shfl_xor(npd, sft, 64);
    }
    if (lane == 0) { red[w][0] = l; red[w][1] = o; red[w][2] = c; red[w][3] = npd; }
    __syncthreads();
    if (t == 0) {
        double L = 0, O = 0, Cp = 0, N = 0;
        #pragma unroll
        for (int j = 0; j < 4; ++j) { L += red[j][0]; O += red[j][1]; Cp += red[j][2]; N += red[j][3]; }
        out[0] = (float)(L / N);
        out[1] = (float)((Cp + csel[0]) / N);
        out[2] = (float)(O / N);
    }
}

extern "C" void kernel_launch(void* const* d_in, const int* in_sizes, int n_in,
                              void* d_out, int out_size, void* d_ws, size_t ws_size,
                              hipStream_t stream) {
    const float* loc_data  = (const float*)d_in[0];
    const float* conf_data = (const float*)d_in[1];
    const float* occ_data  = (const float*)d_in[2];
    const float* loc_t     = (const float*)d_in[3];
    const int*   conf_t    = (const int*)d_in[4];
    const float* occ_t     = (const float*)d_in[5];

    char* ws = (char*)d_ws;
    double* csel   = (double*)ws;            // 1 double
    int*    numpos = (int*)(ws + 64);        // 64 ints
    double* acc    = (double*)(ws + 512);    // NSLOT*3 doubles
    float*  mine   = (float*)(ws + 8192);    // BB*PP floats

    hipMemsetAsync(ws, 0, 8192, stream);

    k_main<<<NTILES, 256, 0, stream>>>(loc_data, conf_data, occ_data, loc_t,
                                       conf_t, occ_t, acc, numpos, mine);
    k_select<<<BB, 1024, 0, stream>>>(mine, numpos, csel);
    k_final<<<1, 256, 0, stream>>>(acc, csel, numpos, (float*)d_out);
}

// Round 3
// 244.994 us; speedup vs baseline: 2.0406x; 1.3614x over previous
//
#include <hip/hip_runtime.h>
#include <stdint.h>

#define BB 64
#define PP 24656
#define CC 81
#define NEGPOS 3
#define RPT 16                     // rows per tile (one tile per wave)
#define TB (RPT * CC * 4)          // 5184 bytes
#define NT ((BB * PP) / RPT)       // 98624 tiles exactly
#define TPB (PP / RPT)             // 1541 tiles per batch row exactly
#define NSLOT 256
#define NBLK 1792                  // 7 blocks/CU * 256 CU

// ws layout:
//   [0]      double csel
//   [64]     int num_pos[64]
//   [512]    double acc[NSLOT*3]
//   [8192]   float mine[BB*PP]

typedef unsigned int u32;

__device__ __forceinline__ void gload_lds16(const void* g, void* l) {
    __builtin_amdgcn_global_load_lds(
        (const __attribute__((address_space(1))) u32*)g,
        (__attribute__((address_space(3))) u32*)l, 16, 0, 0);
}
__device__ __forceinline__ void gload_lds4(const void* g, void* l) {
    __builtin_amdgcn_global_load_lds(
        (const __attribute__((address_space(1))) u32*)g,
        (__attribute__((address_space(3))) u32*)l, 4, 0, 0);
}

__global__ __launch_bounds__(256, 7) void k_main(
    const float* __restrict__ loc_data,
    const float* __restrict__ conf_data,
    const float* __restrict__ occ_data,
    const float* __restrict__ loc_t,
    const int*   __restrict__ conf_t,
    const float* __restrict__ occ_t,
    double* __restrict__ acc,     // NSLOT*3
    int* __restrict__ num_pos,    // 64
    float* __restrict__ mine)     // BB*PP
{
    __shared__ __align__(16) float tile[4 * RPT * CC];   // 4 waves * 5184 B = 20736 B
    __shared__ double red[4][3];

    const int t = threadIdx.x;
    const int w = t >> 6;
    const int lane = t & 63;
    const int r = lane >> 2;        // row within tile 0..15
    const int s = lane & 3;         // quarter-row segment
    float* wtile = tile + w * (RPT * CC);
    char* wlds = (char*)wtile;
    const int wave_id = blockIdx.x * 4 + w;
    const int n_waves = NBLK * 4;

    double a_l = 0.0, a_o = 0.0, a_cp = 0.0;

    for (int td = wave_id; td < NT; td += n_waves) {
        const char* gb = (const char*)conf_data + (long)td * TB;

        // make sure last iteration's ds_reads fully retired before overwriting slice
        asm volatile("s_waitcnt lgkmcnt(0)" ::: "memory");
        #pragma unroll
        for (int c = 0; c < 5; ++c)
            gload_lds16(gb + (c << 10) + (lane << 4), wlds + (c << 10));
        if (lane < 16)
            gload_lds4(gb + 5120 + (lane << 2), wlds + 5120);
        asm volatile("s_waitcnt vmcnt(0)" ::: "memory");
        // wave reads only its own slice -> no __syncthreads needed

        const float* rp = wtile + r * CC;
        const int start = (s == 0) ? 0 : (s * 20 + 1);   // 0..20 | 21..40 | 41..60 | 61..80
        float sum = (s == 0) ? __expf(rp[20]) : 0.0f;
        #pragma unroll
        for (int j = 0; j < 20; ++j) sum += __expf(rp[start + j]);
        sum += __shfl_xor(sum, 1, 64);
        sum += __shfl_xor(sum, 2, 64);   // all 4 lanes of a row now hold the row sum

        bool pos = false;
        const long i = (long)td * RPT + r;
        if (s == 0) {
            const int tc = conf_t[i];
            const float cat = rp[tc];
            const float diff = __logf(sum) - cat;   // lse - conf_at_t, >= 0
            pos = tc > 0;
            if (pos) {
                a_cp += (double)diff;
                const float4 ld4 = *(const float4*)(loc_data + i * 4);
                const float4 lt4 = *(const float4*)(loc_t + i * 4);
                float sl = 0.0f;
                { float d = ld4.x - lt4.x, ad = fabsf(d); sl += (ad < 1.f) ? 0.5f*d*d : ad - 0.5f; }
                { float d = ld4.y - lt4.y, ad = fabsf(d); sl += (ad < 1.f) ? 0.5f*d*d : ad - 0.5f; }
                { float d = ld4.z - lt4.z, ad = fabsf(d); sl += (ad < 1.f) ? 0.5f*d*d : ad - 0.5f; }
                { float d = ld4.w - lt4.w, ad = fabsf(d); sl += (ad < 1.f) ? 0.5f*d*d : ad - 0.5f; }
                a_l += (double)sl;
                const float ot = occ_t[i];
                if (ot != -1.0f) { const float dd = occ_data[i] - ot; a_o += (double)(dd * dd); }
                mine[i] = 0.0f;
            } else {
                mine[i] = fmaxf(diff, 0.0f);
            }
        }
        const unsigned long long bal = __ballot(pos);
        if (bal != 0ull && lane == 0)
            atomicAdd(&num_pos[td / TPB], (int)__popcll(bal));
    }

    #pragma unroll
    for (int sft = 1; sft < 64; sft <<= 1) {
        a_l  += __shfl_xor(a_l,  sft, 64);
        a_o  += __shfl_xor(a_o,  sft, 64);
        a_cp += __shfl_xor(a_cp, sft, 64);
    }
    if (lane == 0) { red[w][0] = a_l; red[w][1] = a_o; red[w][2] = a_cp; }
    __syncthreads();
    if (t == 0) {
        double x0 = red[0][0] + red[1][0] + red[2][0] + red[3][0];
        double x1 = red[0][1] + red[1][1] + red[2][1] + red[3][1];
        double x2 = red[0][2] + red[1][2] + red[2][2] + red[3][2];
        const int slot = blockIdx.x & (NSLOT - 1);
        atomicAdd(&acc[slot * 3 + 0], x0);
        atomicAdd(&acc[slot * 3 + 1], x1);
        atomicAdd(&acc[slot * 3 + 2], x2);
    }
}

// One block per batch row, values register-resident (25 per thread).
__global__ __launch_bounds__(1024) void k_select(
    const float* __restrict__ mine,
    const int* __restrict__ num_pos,
    double* __restrict__ csel)
{
    __shared__ u32 hist16[16][256];
    __shared__ u32 htot[256];
    __shared__ u32 sh_prefix, sh_kk;
    __shared__ double dred[16];
    __shared__ u32 cred[16];

    const int b = blockIdx.x;
    const int t = threadIdx.x;
    const int w = t >> 6;
    const int lane = t & 63;
    const float* row = mine + (long)b * PP;

    u32 u[25];
    #pragma unroll
    for (int r = 0; r < 25; ++r) {
        const int idx = t + (r << 10);
        u[r] = (idx < PP) ? __float_as_uint(row[idx]) : 0u;  // +0.0 pads sort last
    }

    const int np = num_pos[b];
    int k = NEGPOS * np;
    if (k > PP - 1) k = PP - 1;
    if (k <= 0) return;   // uniform across block

    u32 prefix = 0, mask = 0, kk = (u32)k;

    for (int pass = 0; pass < 4; ++pass) {
        const int shift = 24 - 8 * pass;
        for (int z = t; z < 16 * 256; z += 1024) ((u32*)hist16)[z] = 0;
        __syncthreads();
        #pragma unroll
        for (int r = 0; r < 25; ++r) {
            const u32 uu = u[r];
            if ((uu & mask) == prefix)
                atomicAdd(&hist16[w][(uu >> shift) & 255], 1u);
        }
        __syncthreads();
        if (t < 256) {
            u32 s2 = 0;
            #pragma unroll
            for (int j = 0; j < 16; ++j) s2 += hist16[j][t];
            htot[t] = s2;
        }
        __syncthreads();
        if (t < 256) {
            u32 above = 0;
            for (int bb = t + 1; bb < 256; ++bb) above += htot[bb];
            if (above < kk && above + htot[t] >= kk) {   // exactly one bin
                sh_prefix = prefix | ((u32)t << shift);
                sh_kk = kk - above;
            }
        }
        __syncthreads();
        prefix = sh_prefix;
        kk = sh_kk;
        mask |= (0xFFu << shift);
        __syncthreads();
    }

    const u32 thr_bits = prefix;
    const float thr = __uint_as_float(thr_bits);

    double ssum = 0.0;
    u32 cnt = 0;
    #pragma unroll
    for (int r = 0; r < 25; ++r) {
        const u32 uu = u[r];
        if (uu > thr_bits) { ssum += (double)__uint_as_float(uu); cnt++; }
    }
    #pragma unroll
    for (int sft = 1; sft < 64; sft <<= 1) {
        ssum += __shfl_xor(ssum, sft, 64);
        cnt  += __shfl_xor(cnt,  sft, 64);
    }
    if (lane == 0) { dred[w] = ssum; cred[w] = cnt; }
    __syncthreads();
    if (t == 0) {
        double S = 0.0; u32 cg = 0;
        #pragma unroll
        for (int j = 0; j < 16; ++j) { S += dred[j]; cg += cred[j]; }
        S += (double)(k - (int)cg) * (double)thr;
        atomicAdd(csel, S);
    }
}

__global__ __launch_bounds__(256) void k_final(
    const double* __restrict__ acc,
    const double* __restrict__ csel,
    const int* __restrict__ num_pos,
    float* __restrict__ out)
{
    __shared__ double red[4][4];
    const int t = threadIdx.x;
    const int w = t >> 6;
    const int lane = t & 63;

    double l = acc[t * 3 + 0];
    double o = acc[t * 3 + 1];
    double c = acc[t * 3 + 2];
    double npd = (t < BB) ? (double)num_pos[t] : 0.0;
    #pragma unroll
    for (int sft = 1; sft < 64; sft <<= 1) {
        l   += __shfl_xor(l,   sft, 64);
        o   += __shfl_xor(o,   sft, 64);
        c   += __shfl_xor(c,   sft, 64);
        npd += __shfl_xor(npd, sft, 64);
    }
    if (lane == 0) { red[w][0] = l; red[w][1] = o; red[w][2] = c; red[w][3] = npd; }
    __syncthreads();
    if (t == 0) {
        double L = 0, O = 0, Cp = 0, N = 0;
        #pragma unroll
        for (int j = 0; j < 4; ++j) { L += red[j][0]; O += red[j][1]; Cp += red[j][2]; N += red[j][3]; }
        out[0] = (float)(L / N);
        out[1] = (float)((Cp + csel[0]) / N);
        out[2] = (float)(O / N);
    }
}

extern "C" void kernel_launch(void* const* d_in, const int* in_sizes, int n_in,
                              void* d_out, int out_size, void* d_ws, size_t ws_size,
                              hipStream_t stream) {
    const float* loc_data  = (const float*)d_in[0];
    const float* conf_data = (const float*)d_in[1];
    const float* occ_data  = (const float*)d_in[2];
    const float* loc_t     = (const float*)d_in[3];
    const int*   conf_t    = (const int*)d_in[4];
    const float* occ_t     = (const float*)d_in[5];

    char* ws = (char*)d_ws;
    double* csel   = (double*)ws;            // 1 double
    int*    numpos = (int*)(ws + 64);        // 64 ints
    double* acc    = (double*)(ws + 512);    // NSLOT*3 doubles
    float*  mine   = (float*)(ws + 8192);    // BB*PP floats

    hipMemsetAsync(ws, 0, 8192, stream);

    k_main<<<NBLK, 256, 0, stream>>>(loc_data, conf_data, occ_data, loc_t,
                                     conf_t, occ_t, acc, numpos, mine);
    k_select<<<BB, 1024, 0, stream>>>(mine, numpos, csel);
    k_final<<<1, 256, 0, stream>>>(acc, csel, numpos, (float*)d_out);
}